// Round 11
// baseline (5705.441 us; speedup 1.0000x reference)
//
#include <hip/hip_runtime.h>
#include <math.h>

// Problem constants
#define BN   128      // batch
#define TN   1440     // timesteps
#define HN   512      // hidden
#define GBn  8        // batch groups
#define BSn  16       // batches per group
#define GPn  4        // batch-group PAIRS (one pair per WG)
#define GCn  32       // column groups
#define HCn  16       // h-cols per WG
#define WST  536      // LDS row stride in f16: 268 dw == 12 mod 32 -> conflict-free b128 frag reads

using f16 = _Float16;
typedef f16   f16x8 __attribute__((ext_vector_type(8)));
typedef float f32x4 __attribute__((ext_vector_type(4)));
typedef unsigned int       uint32;
typedef unsigned long long u64;

// ws layout (bytes):
//   [0,1024)             flags int [8 gb][32 gc]   (gb = ring id, dense as in R0)
//   [1024,2048)          scal: [0]=half_tau, [1]=trigger
//   [2048,526336)        hbufP uint32 [2 buf][128 b][512 k]  (lo16=f16 hi, hi16=f16 lo*2048)
//   [526336,1263616)     xsf f32 [128][1440]
#define OFF_SCAL 1024
#define OFF_HBUF 2048
#define OFF_XSF  (2048 + 2 * BN * HN * 4)

// ---------------- K0: scalar prep (grads -> half_tau, trigger) ----------------
__global__ void k_prep(const float* __restrict__ w_ih, float* __restrict__ scal) {
    __shared__ float ssum[4];
    float s = 0.0f;
    for (int i = threadIdx.x; i < 3 * HN * 2; i += 256) s += w_ih[i];
    for (int o = 32; o >= 1; o >>= 1) s += __shfl_down(s, o, 64);
    if ((threadIdx.x & 63) == 0) ssum[threadIdx.x >> 6] = s;
    __syncthreads();
    if (threadIdx.x == 0) {
        float tot = ssum[0] + ssum[1] + ssum[2] + ssum[3];
        float grads = tot / 3072.0f - 1.0f;
        float tau_new = 6.0f + grads * 0.1f;
        bool trig = (tau_new >= 1.0f) && (tau_new != 6.0f);
        scal[0] = rintf(tau_new * 0.5f);   // round-half-even matches jnp.round
        scal[1] = trig ? 1.0f : 0.0f;
    }
}

// ---------------- K1: NaN-fix + belief_fill (one wave per batch row) ----------------
__global__ void k_fill(const float* __restrict__ inp, const float* __restrict__ scal,
                       float* __restrict__ xsf) {
    const int b = blockIdx.x;
    const int lane = threadIdx.x;            // 0..63
    const float ht = scal[0];
    const bool trig = scal[1] != 0.0f;
    const float* xrow = inp + (size_t)b * 3 * TN;       // channel 0 = xs
    const float* mrow = xrow + 2 * TN;                   // channel 2 = mask
    const int CH = 23;                                   // 64*23 = 1472 >= 1440
    const int start = lane * CH;

    if (!trig) {
        for (int i = 0; i < CH; ++i) {
            int t = start + i;
            if (t < TN) { float x = xrow[t]; if (x != x) x = -1.0f; xsf[(size_t)b * TN + t] = x; }
        }
        return;
    }
    int pm = -1;
#pragma unroll
    for (int i = 0; i < CH; ++i) { int t = start + i; if (t < TN && mrow[t] == 1.0f) pm = t; }
    int incl = pm;
    for (int o = 1; o < 64; o <<= 1) { int v = __shfl_up(incl, o, 64); if (lane >= o) incl = max(incl, v); }
    int pexcl = __shfl_up(incl, 1, 64); if (lane == 0) pexcl = -1;
    int nm = TN;
#pragma unroll
    for (int i = CH - 1; i >= 0; --i) { int t = start + i; if (t < TN && mrow[t] == 1.0f) nm = t; }
    int incl2 = nm;
    for (int o = 1; o < 64; o <<= 1) { int v = __shfl_down(incl2, o, 64); if (lane + o < 64) incl2 = min(incl2, v); }
    int nexcl = __shfl_down(incl2, 1, 64); if (lane == 63) nexcl = TN;
    int narr[23];
    int runn = nexcl;
#pragma unroll
    for (int i = CH - 1; i >= 0; --i) {
        int t = start + i;
        if (t < TN) { if (mrow[t] == 1.0f) runn = t; narr[i] = runn; } else narr[i] = TN;
    }
    int runp = pexcl;
#pragma unroll
    for (int i = 0; i < CH; ++i) {
        int t = start + i;
        if (t >= TN) break;
        float x = xrow[t]; if (x != x) x = -1.0f;
        if (mrow[t] == 1.0f) runp = t;
        int pv = runp, nv = narr[i];
        int pc = min(max(pv, 0), TN - 1), nc = min(max(nv, 0), TN - 1);
        float xp = xrow[pc]; if (xp != xp) xp = -1.0f;
        float xn = xrow[nc]; if (xn != xn) xn = -1.0f;
        bool use_n = (nv < TN) && ((float)t >= (float)nv - ht);
        bool use_p = (pv >= 0) && ((float)t <= (float)pv + ht);
        float o = use_n ? xn : (use_p ? xp : x);
        xsf[(size_t)b * TN + t] = o;
    }
}

// ---------------- K2: persistent GRU, TWO time-multiplexed rings per WG ----------------
// grid 128 = 4 batch-group pairs x 32 col-groups; block 256 (4 waves); 1 WG/CU.
// Each WG hosts ring A (gb=2gp) and ring B (gb=2gp+1). Per iteration it advances both
// rings one step, A-half then B-half, with the byte-identical proven R0 protocol per
// ring (relaxed agent atomics, per-WG flags, __syncthreads vmcnt-drain before the flag
// store, parity double-buffer). Purpose: ring A's exchange legs (drain ack, flag
// visibility, peers' polls) execute WHILE this WG computes ring B's half, and vice
// versa -- hiding the ~4-hop L3 chain that 10 rounds showed cannot be shortened.
// Weights (bfh/bfl) depend only on gc -> shared by both halves (no extra VGPR cost).
// Software pipeline: poll B(t)+issue B-loads before MFMA A; poll A(t+1)+issue A-loads
// after MFMA B -> each ring's load RTT hides under the other ring's MFMA.
// Correctness per ring is the R0 argument verbatim: flagX(t+1) is stored after (a) the
// drain barrier acks all publish-X stores and (b) program order placed all step-t
// X-loads (consumed in stage-X before that barrier) -- so flagX(t+1) from every peer
// implies h_t^X fully consumed, making the parity overwrite at t+2 safe. The two rings
// are disjoint (different batch rows, different flags); interleaving them in one WG
// adds only program-order edges, no cycles -> no deadlock. G16-safe: agent scope
// everywhere, no WG->XCD placement assumptions.
__global__ __launch_bounds__(256, 1) void k_gru(
    const float* __restrict__ inp, const float* __restrict__ w_ih,
    const float* __restrict__ w_hh, const float* __restrict__ b_ih,
    const float* __restrict__ b_hh, const float* __restrict__ w_fc,
    const float* __restrict__ b_fc, const float* __restrict__ xsf,
    uint32* __restrict__ hbufP, int* __restrict__ flags, float* __restrict__ out) {
    __shared__ __align__(16) f16 sHhi[BSn * WST];
    __shared__ __align__(16) f16 sHlo[BSn * WST];
    __shared__ float sGh[3][BSn][HCn + 1];
    __shared__ float sWi0[48], sWi1[48], sBias[48];

    const int tid = threadIdx.x;
    const int gp = blockIdx.x & 3;            // pair id 0..3
    const int gc = blockIdx.x >> 2;           // 0..31
    const int gbA = gp * 2, gbB = gp * 2 + 1;
    const int lane = tid & 63;
    const int wv   = tid >> 6;
    const int bs   = tid >> 4;        // gate-math row 0..15
    const int j    = tid & 15;
    const int bglobA = gbA * BSn + bs;
    const int bglobB = gbB * BSn + bs;
    const int pcol  = gc * HCn + j;
    const int frow = lane & 15;       // MFMA m (A) / n (B) index
    const int kgrp = lane >> 4;       // MFMA k-group

    if (tid < 48) {
        int gate = tid >> 4, jj = tid & 15;
        int grow = gate * HN + gc * HCn + jj;
        sWi0[tid]  = w_ih[grow * 2 + 0];
        sWi1[tid]  = w_ih[grow * 2 + 1];
        sBias[tid] = b_ih[grow] + b_hh[grow];
    }

    // one-time: weight B-fragments into VGPRs (hi + lo*2^11 split) -- shared by A and B
    f16x8 bfh[16], bfl[16];
    if (wv < 3) {
        const float* wrow = w_hh + (size_t)(wv * HN + gc * HCn + frow) * HN;
#pragma unroll
        for (int c = 0; c < 16; ++c) {
            const int k0 = (c * 4 + kgrp) * 8;
#pragma unroll
            for (int u = 0; u < 8; ++u) {
                float w = wrow[k0 + u];
                f16 hi = (f16)w;
                bfh[c][u] = hi;
                bfl[c][u] = (f16)((w - (float)hi) * 2048.0f);
            }
        }
    }
    __syncthreads();

    int* flagsA = flags + gbA * GCn;
    int* flagsB = flags + gbB * GCn;
    const f16x8* pAhi = (const f16x8*)(sHhi + frow * WST);
    const f16x8* pAlo = (const f16x8*)(sHlo + frow * WST);
    float hA = 0.0f, hB = 0.0f;
    u64 hvA[16], hvB[16];

    // prologue: issue ring-A loads for t=0 (buf0 = memset h_0; flags>=0 trivially)
    {
        const uint32* srcA = hbufP + (size_t)gbA * BSn * HN;
#pragma unroll
        for (int i = 0; i < 16; ++i)
            hvA[i] = __hip_atomic_load((const u64*)(srcA + (size_t)i * HN) + tid,
                                       __ATOMIC_RELAXED, __HIP_MEMORY_SCOPE_AGENT);
    }

    for (int t = 0; t < TN; ++t) {
        float xsvA = xsf[(size_t)bglobA * TN + t];
        float mkvA = inp[((size_t)bglobA * 3 + 2) * TN + t];
        float xsvB = xsf[(size_t)bglobB * TN + t];
        float mkvB = inp[((size_t)bglobB * 3 + 2) * TN + t];

        // ---- A half ----
        // stage A (hvA prefetched last iteration / prologue)
#pragma unroll
        for (int i = 0; i < 16; ++i) {
            uint32 d0 = (uint32)hvA[i], d1 = (uint32)(hvA[i] >> 32);
            ((uint32*)(sHhi + i * WST))[tid] = __builtin_amdgcn_perm(d1, d0, 0x05040100u);
            ((uint32*)(sHlo + i * WST))[tid] = __builtin_amdgcn_perm(d1, d0, 0x07060302u);
        }
        __syncthreads();                                   // B1: sH(A) visible
        // poll ring B, issue B loads -> RTT hides under MFMA A
        if (lane < GCn) {
            while (__hip_atomic_load(&flagsB[lane], __ATOMIC_RELAXED,
                                     __HIP_MEMORY_SCOPE_AGENT) < t) {}
        }
        {
            const uint32* srcB = hbufP + ((size_t)(t & 1) * BN + gbB * BSn) * HN;
#pragma unroll
            for (int i = 0; i < 16; ++i)
                hvB[i] = __hip_atomic_load((const u64*)(srcB + (size_t)i * HN) + tid,
                                           __ATOMIC_RELAXED, __HIP_MEMORY_SCOPE_AGENT);
        }
        // MFMA A (6 accumulators, dep-chain 8 -- R9)
        if (wv < 3) {
            f32x4 ah0 = {0.f,0.f,0.f,0.f}, ah1 = {0.f,0.f,0.f,0.f};
            f32x4 al0 = {0.f,0.f,0.f,0.f}, al1 = {0.f,0.f,0.f,0.f};
            f32x4 bl0 = {0.f,0.f,0.f,0.f}, bl1 = {0.f,0.f,0.f,0.f};
#pragma unroll
            for (int c = 0; c < 16; c += 2) {
                f16x8 ha = pAhi[c * 4 + kgrp];
                f16x8 la = pAlo[c * 4 + kgrp];
                f16x8 hb = pAhi[(c + 1) * 4 + kgrp];
                f16x8 lb = pAlo[(c + 1) * 4 + kgrp];
                ah0 = __builtin_amdgcn_mfma_f32_16x16x32_f16(ha, bfh[c],     ah0, 0, 0, 0);
                ah1 = __builtin_amdgcn_mfma_f32_16x16x32_f16(hb, bfh[c + 1], ah1, 0, 0, 0);
                al0 = __builtin_amdgcn_mfma_f32_16x16x32_f16(ha, bfl[c],     al0, 0, 0, 0);
                al1 = __builtin_amdgcn_mfma_f32_16x16x32_f16(hb, bfl[c + 1], al1, 0, 0, 0);
                bl0 = __builtin_amdgcn_mfma_f32_16x16x32_f16(la, bfh[c],     bl0, 0, 0, 0);
                bl1 = __builtin_amdgcn_mfma_f32_16x16x32_f16(lb, bfh[c + 1], bl1, 0, 0, 0);
            }
#pragma unroll
            for (int r = 0; r < 4; ++r)
                sGh[wv][kgrp * 4 + r][frow] =
                    (ah0[r] + ah1[r]) + (al0[r] + al1[r] + bl0[r] + bl1[r]) * (1.0f / 2048.0f);
        }
        __syncthreads();                                   // B2: sGh(A) visible
        // gate A + publish A
        {
            float ghr = sGh[0][bs][j], ghz = sGh[1][bs][j], ghn = sGh[2][bs][j];
            float gir = xsvA * sWi0[j]      + mkvA * sWi1[j]      + sBias[j];
            float giz = xsvA * sWi0[16 + j] + mkvA * sWi1[16 + j] + sBias[16 + j];
            float gin = xsvA * sWi0[32 + j] + mkvA * sWi1[32 + j] + sBias[32 + j];
            float rg = __fdividef(1.0f, 1.0f + __expf(-(gir + ghr)));
            float zg = __fdividef(1.0f, 1.0f + __expf(-(giz + ghz)));
            float xt = gin + rg * ghn;
            float ng = __fdividef(2.0f, 1.0f + __expf(-2.0f * xt)) - 1.0f;
            hA = (1.0f - zg) * ng + zg * hA;
            f16 hi = (f16)hA;
            f16 lo = (f16)((hA - (float)hi) * 2048.0f);
            uint32 pk = (uint32)__builtin_bit_cast(unsigned short, hi)
                      | ((uint32)__builtin_bit_cast(unsigned short, lo) << 16);
            __hip_atomic_store(&hbufP[((size_t)((t + 1) & 1) * BN + bglobA) * HN + pcol], pk,
                               __ATOMIC_RELAXED, __HIP_MEMORY_SCOPE_AGENT);
        }
        // stage B (hvB issued pre-MFMA-A; sH overwrite safe: all waves past B2)
#pragma unroll
        for (int i = 0; i < 16; ++i) {
            uint32 d0 = (uint32)hvB[i], d1 = (uint32)(hvB[i] >> 32);
            ((uint32*)(sHhi + i * WST))[tid] = __builtin_amdgcn_perm(d1, d0, 0x05040100u);
            ((uint32*)(sHlo + i * WST))[tid] = __builtin_amdgcn_perm(d1, d0, 0x07060302u);
        }
        __syncthreads();                 // B3: drains vmcnt(0) -> publish-A acked; sH(B) visible
        if (tid == 0)
            __hip_atomic_store(&flagsA[gc], t + 1, __ATOMIC_RELAXED, __HIP_MEMORY_SCOPE_AGENT);

        // ---- B half ----
        // MFMA B
        if (wv < 3) {
            f32x4 ah0 = {0.f,0.f,0.f,0.f}, ah1 = {0.f,0.f,0.f,0.f};
            f32x4 al0 = {0.f,0.f,0.f,0.f}, al1 = {0.f,0.f,0.f,0.f};
            f32x4 bl0 = {0.f,0.f,0.f,0.f}, bl1 = {0.f,0.f,0.f,0.f};
#pragma unroll
            for (int c = 0; c < 16; c += 2) {
                f16x8 ha = pAhi[c * 4 + kgrp];
                f16x8 la = pAlo[c * 4 + kgrp];
                f16x8 hb = pAhi[(c + 1) * 4 + kgrp];
                f16x8 lb = pAlo[(c + 1) * 4 + kgrp];
                ah0 = __builtin_amdgcn_mfma_f32_16x16x32_f16(ha, bfh[c],     ah0, 0, 0, 0);
                ah1 = __builtin_amdgcn_mfma_f32_16x16x32_f16(hb, bfh[c + 1], ah1, 0, 0, 0);
                al0 = __builtin_amdgcn_mfma_f32_16x16x32_f16(ha, bfl[c],     al0, 0, 0, 0);
                al1 = __builtin_amdgcn_mfma_f32_16x16x32_f16(hb, bfl[c + 1], al1, 0, 0, 0);
                bl0 = __builtin_amdgcn_mfma_f32_16x16x32_f16(la, bfh[c],     bl0, 0, 0, 0);
                bl1 = __builtin_amdgcn_mfma_f32_16x16x32_f16(lb, bfh[c + 1], bl1, 0, 0, 0);
            }
#pragma unroll
            for (int r = 0; r < 4; ++r)
                sGh[wv][kgrp * 4 + r][frow] =
                    (ah0[r] + ah1[r]) + (al0[r] + al1[r] + bl0[r] + bl1[r]) * (1.0f / 2048.0f);
        }
        __syncthreads();                                   // B4: sGh(B) visible
        // poll ring A for t+1, issue next A loads -> RTT hides under gate B + barriers
        if (t + 1 < TN) {
            if (lane < GCn) {
                while (__hip_atomic_load(&flagsA[lane], __ATOMIC_RELAXED,
                                         __HIP_MEMORY_SCOPE_AGENT) < t + 1) {}
            }
            const uint32* srcA = hbufP + ((size_t)((t + 1) & 1) * BN + gbA * BSn) * HN;
#pragma unroll
            for (int i = 0; i < 16; ++i)
                hvA[i] = __hip_atomic_load((const u64*)(srcA + (size_t)i * HN) + tid,
                                           __ATOMIC_RELAXED, __HIP_MEMORY_SCOPE_AGENT);
        }
        // gate B + publish B
        {
            float ghr = sGh[0][bs][j], ghz = sGh[1][bs][j], ghn = sGh[2][bs][j];
            float gir = xsvB * sWi0[j]      + mkvB * sWi1[j]      + sBias[j];
            float giz = xsvB * sWi0[16 + j] + mkvB * sWi1[16 + j] + sBias[16 + j];
            float gin = xsvB * sWi0[32 + j] + mkvB * sWi1[32 + j] + sBias[32 + j];
            float rg = __fdividef(1.0f, 1.0f + __expf(-(gir + ghr)));
            float zg = __fdividef(1.0f, 1.0f + __expf(-(giz + ghz)));
            float xt = gin + rg * ghn;
            float ng = __fdividef(2.0f, 1.0f + __expf(-2.0f * xt)) - 1.0f;
            hB = (1.0f - zg) * ng + zg * hB;
            f16 hi = (f16)hB;
            f16 lo = (f16)((hB - (float)hi) * 2048.0f);
            uint32 pk = (uint32)__builtin_bit_cast(unsigned short, hi)
                      | ((uint32)__builtin_bit_cast(unsigned short, lo) << 16);
            __hip_atomic_store(&hbufP[((size_t)((t + 1) & 1) * BN + bglobB) * HN + pcol], pk,
                               __ATOMIC_RELAXED, __HIP_MEMORY_SCOPE_AGENT);
        }
        __syncthreads();                 // B5: drains vmcnt(0) -> publish-B acked (also next-A loads)
        if (tid == 0)
            __hip_atomic_store(&flagsB[gc], t + 1, __ATOMIC_RELAXED, __HIP_MEMORY_SCOPE_AGENT);
    }

    // final FC: out[b] = sum_k h[b][k]*w_fc[k] + b_fc   (both rings)
    float wfc = w_fc[pcol];
    float partA = hA * wfc, partB = hB * wfc;
#pragma unroll
    for (int o = 1; o < 16; o <<= 1) {
        partA += __shfl_xor(partA, o, 64);
        partB += __shfl_xor(partB, o, 64);
    }
    if (j == 0) {
        if (gc == 0) { partA += b_fc[0]; partB += b_fc[0]; }
        atomicAdd(&out[bglobA], partA);
        atomicAdd(&out[bglobB], partB);
    }
}

extern "C" void kernel_launch(void* const* d_in, const int* in_sizes, int n_in,
                              void* d_out, int out_size, void* d_ws, size_t ws_size,
                              hipStream_t stream) {
    const float* inp  = (const float*)d_in[0];
    const float* w_ih = (const float*)d_in[1];
    const float* w_hh = (const float*)d_in[2];
    const float* b_ih = (const float*)d_in[3];
    const float* b_hh = (const float*)d_in[4];
    const float* w_fc = (const float*)d_in[5];
    const float* b_fc = (const float*)d_in[6];
    float* out = (float*)d_out;
    char* ws = (char*)d_ws;
    int*    flags = (int*)ws;
    float*  scal  = (float*)(ws + OFF_SCAL);
    uint32* hbufP = (uint32*)(ws + OFF_HBUF);
    float*  xsf   = (float*)(ws + OFF_XSF);

    // zero: flags + scal + packed-h buf0 (= h_0 = 0); d_out (atomicAdd target)
    hipMemsetAsync(ws, 0, OFF_HBUF + BN * HN * 4, stream);
    hipMemsetAsync(d_out, 0, BN * sizeof(float), stream);
    k_prep<<<1, 256, 0, stream>>>(w_ih, scal);
    k_fill<<<BN, 64, 0, stream>>>(inp, scal, xsf);
    k_gru<<<GPn * GCn, 256, 0, stream>>>(inp, w_ih, w_hh, b_ih, b_hh, w_fc, b_fc,
                                         xsf, hbufP, flags, out);
}

// Round 13
// 3665.100 us; speedup vs baseline: 1.5567x; 1.5567x over previous
//
#include <hip/hip_runtime.h>
#include <math.h>

// Problem constants
#define BN   128      // batch
#define TN   1440     // timesteps
#define HN   512      // hidden
#define GBn  8        // batch groups
#define BSn  16       // batches per group
#define GCn  32       // column groups
#define HCn  16       // h-cols per WG
#define WST  536      // LDS row stride in f16: 268 dw == 12 mod 32 -> conflict-free b128 frag reads

using f16 = _Float16;
typedef f16   f16x8 __attribute__((ext_vector_type(8)));
typedef float f32x4 __attribute__((ext_vector_type(4)));
typedef unsigned int       uint32;
typedef unsigned long long u64;

// ws layout (bytes):
//   [0,1024)             flags[8][32] int
//   [1024,2048)          scal: [0]=half_tau, [1]=trigger
//   [2048,526336)        hbufP uint32 [2 buf][128 b][512 k]  (lo16=f16 hi, hi16=f16 lo*2048)
//   [526336,1263616)     xsf f32 [128][1440]
#define OFF_SCAL 1024
#define OFF_HBUF 2048
#define OFF_XSF  (2048 + 2 * BN * HN * 4)

// ---------------- K0: scalar prep (grads -> half_tau, trigger) ----------------
__global__ void k_prep(const float* __restrict__ w_ih, float* __restrict__ scal) {
    __shared__ float ssum[4];
    float s = 0.0f;
    for (int i = threadIdx.x; i < 3 * HN * 2; i += 256) s += w_ih[i];
    for (int o = 32; o >= 1; o >>= 1) s += __shfl_down(s, o, 64);
    if ((threadIdx.x & 63) == 0) ssum[threadIdx.x >> 6] = s;
    __syncthreads();
    if (threadIdx.x == 0) {
        float tot = ssum[0] + ssum[1] + ssum[2] + ssum[3];
        float grads = tot / 3072.0f - 1.0f;
        float tau_new = 6.0f + grads * 0.1f;
        bool trig = (tau_new >= 1.0f) && (tau_new != 6.0f);
        scal[0] = rintf(tau_new * 0.5f);   // round-half-even matches jnp.round
        scal[1] = trig ? 1.0f : 0.0f;
    }
}

// ---------------- K1: NaN-fix + belief_fill (one wave per batch row) ----------------
__global__ void k_fill(const float* __restrict__ inp, const float* __restrict__ scal,
                       float* __restrict__ xsf) {
    const int b = blockIdx.x;
    const int lane = threadIdx.x;            // 0..63
    const float ht = scal[0];
    const bool trig = scal[1] != 0.0f;
    const float* xrow = inp + (size_t)b * 3 * TN;       // channel 0 = xs
    const float* mrow = xrow + 2 * TN;                   // channel 2 = mask
    const int CH = 23;                                   // 64*23 = 1472 >= 1440
    const int start = lane * CH;

    if (!trig) {
        for (int i = 0; i < CH; ++i) {
            int t = start + i;
            if (t < TN) { float x = xrow[t]; if (x != x) x = -1.0f; xsf[(size_t)b * TN + t] = x; }
        }
        return;
    }
    int pm = -1;
#pragma unroll
    for (int i = 0; i < CH; ++i) { int t = start + i; if (t < TN && mrow[t] == 1.0f) pm = t; }
    int incl = pm;
    for (int o = 1; o < 64; o <<= 1) { int v = __shfl_up(incl, o, 64); if (lane >= o) incl = max(incl, v); }
    int pexcl = __shfl_up(incl, 1, 64); if (lane == 0) pexcl = -1;
    int nm = TN;
#pragma unroll
    for (int i = CH - 1; i >= 0; --i) { int t = start + i; if (t < TN && mrow[t] == 1.0f) nm = t; }
    int incl2 = nm;
    for (int o = 1; o < 64; o <<= 1) { int v = __shfl_down(incl2, o, 64); if (lane + o < 64) incl2 = min(incl2, v); }
    int nexcl = __shfl_down(incl2, 1, 64); if (lane == 63) nexcl = TN;
    int narr[23];
    int runn = nexcl;
#pragma unroll
    for (int i = CH - 1; i >= 0; --i) {
        int t = start + i;
        if (t < TN) { if (mrow[t] == 1.0f) runn = t; narr[i] = runn; } else narr[i] = TN;
    }
    int runp = pexcl;
#pragma unroll
    for (int i = 0; i < CH; ++i) {
        int t = start + i;
        if (t >= TN) break;
        float x = xrow[t]; if (x != x) x = -1.0f;
        if (mrow[t] == 1.0f) runp = t;
        int pv = runp, nv = narr[i];
        int pc = min(max(pv, 0), TN - 1), nc = min(max(nv, 0), TN - 1);
        float xp = xrow[pc]; if (xp != xp) xp = -1.0f;
        float xn = xrow[nc]; if (xn != xn) xn = -1.0f;
        bool use_n = (nv < TN) && ((float)t >= (float)nv - ht);
        bool use_p = (pv >= 0) && ((float)t <= (float)pv + ht);
        float o = use_n ? xn : (use_p ? xp : x);
        xsf[(size_t)b * TN + t] = o;
    }
}

// ---------------- K2: persistent column-split GRU, L3-coherent comm ----------------
// grid 256 = 8 batch-groups x 32 col-groups; block 256 (4 waves); 1 WG/CU.
// Protocol (poll, coalesced u64 staging loads, 3 barriers, vmcnt-drain before tid0
// flag), grid mapping (gb = bid&7, XCD-local ring -- R11 measured this is worth 2x on
// FETCH), scopes: byte-identical to R0/R9. Four failed rounds (R2/R4/R8/R12) proved
// the protocol untouchable; R13 only re-partitions the COMPUTE between barriers:
//   K-split waves instead of gate-split: wave wv computes ALL 3 gates over K-slice
//   [128wv, 128wv+128) -- 36 MFMAs/wave on 4 SIMDs vs R9's 48 on 3 (wave 3 idled).
//   Partials to sPart[3][4][16][17]; gate math sums the 4 wave-partials (exact fp32
//   add order change only -- same split-term summation as R9's 6-acc form).
// Keeps R9's fast-math gates + dep-chain-limited accumulators (per-gate chain <= 8).
__global__ __launch_bounds__(256, 1) void k_gru(
    const float* __restrict__ inp, const float* __restrict__ w_ih,
    const float* __restrict__ w_hh, const float* __restrict__ b_ih,
    const float* __restrict__ b_hh, const float* __restrict__ w_fc,
    const float* __restrict__ b_fc, const float* __restrict__ xsf,
    uint32* __restrict__ hbufP, int* __restrict__ flags, float* __restrict__ out) {
    __shared__ __align__(16) f16 sHhi[BSn * WST];
    __shared__ __align__(16) f16 sHlo[BSn * WST];
    __shared__ float sPart[3][4][BSn][HCn + 1];   // [gate][wave][batch-row][col(+pad)]
    __shared__ float sWi0[48], sWi1[48], sBias[48];

    const int tid = threadIdx.x;
    const int gb = blockIdx.x & 7;
    const int gc = blockIdx.x >> 3;
    const int lane = tid & 63;
    const int wv   = tid >> 6;        // K-slice owner: k in [128wv, 128wv+128)
    const int bs   = tid >> 4;        // gate-math row 0..15
    const int j    = tid & 15;
    const int bglob = gb * BSn + bs;
    const int pcol  = gc * HCn + j;
    const int frow = lane & 15;       // MFMA m (A) / n (B) index
    const int kgrp = lane >> 4;       // MFMA k-group

    if (tid < 48) {
        int gate = tid >> 4, jj = tid & 15;
        int grow = gate * HN + gc * HCn + jj;
        sWi0[tid]  = w_ih[grow * 2 + 0];
        sWi1[tid]  = w_ih[grow * 2 + 1];
        sBias[tid] = b_ih[grow] + b_hh[grow];
    }

    // one-time: weight B-fragments into VGPRs (hi + lo*2^11 split).
    // wave wv, gate g, chunk kc: K-offset 128wv + 32kc + 8kgrp.
    f16x8 bfh[3][4], bfl[3][4];
#pragma unroll
    for (int g = 0; g < 3; ++g) {
        const float* wrow = w_hh + (size_t)(g * HN + gc * HCn + frow) * HN;
#pragma unroll
        for (int kc = 0; kc < 4; ++kc) {
            const int k0 = 128 * wv + 32 * kc + 8 * kgrp;
#pragma unroll
            for (int u = 0; u < 8; ++u) {
                float w = wrow[k0 + u];
                f16 hi = (f16)w;
                bfh[g][kc][u] = hi;
                bfl[g][kc][u] = (f16)((w - (float)hi) * 2048.0f);
            }
        }
    }
    __syncthreads();

    int* myflags = flags + gb * GCn;
    const f16x8* pAhi = (const f16x8*)(sHhi + frow * WST);
    const f16x8* pAlo = (const f16x8*)(sHlo + frow * WST);
    float h = 0.0f;

    for (int t = 0; t < TN; ++t) {
        // prefetch driving inputs (independent of sync)
        float xsv = xsf[(size_t)bglob * TN + t];
        float mkv = inp[((size_t)bglob * 3 + 2) * TN + t];
        // 1. every wave polls all 32 peer flags (relaxed atomic load = L3 read)
        if (lane < GCn) {
            while (__hip_atomic_load(&myflags[lane], __ATOMIC_RELAXED, __HIP_MEMORY_SCOPE_AGENT) < t) {}
        }
        // 2. stage h_t into LDS: 16 coherent u64 loads/thread (2 packed dwords of batch row i)
        {
            const uint32* src = hbufP + ((size_t)(t & 1) * BN + gb * BSn) * HN;
            u64 hv[16];
#pragma unroll
            for (int i = 0; i < 16; ++i)
                hv[i] = __hip_atomic_load((const u64*)(src + (size_t)i * HN) + tid,
                                          __ATOMIC_RELAXED, __HIP_MEMORY_SCOPE_AGENT);
#pragma unroll
            for (int i = 0; i < 16; ++i) {
                uint32 d0 = (uint32)hv[i], d1 = (uint32)(hv[i] >> 32);
                ((uint32*)(sHhi + i * WST))[tid] = __builtin_amdgcn_perm(d1, d0, 0x05040100u);
                ((uint32*)(sHlo + i * WST))[tid] = __builtin_amdgcn_perm(d1, d0, 0x07060302u);
            }
        }
        __syncthreads();                                   // B1: sH visible
        // 3. MFMA: ALL 4 waves work. Wave wv: 3 gates x K-slice [128wv,128wv+128)
        //    = 3 x 4 chunks x 3 split-terms = 36 MFMAs; per-gate acc chains 4/8 deep.
        {
            f32x4 acch[3] = {{0.f,0.f,0.f,0.f},{0.f,0.f,0.f,0.f},{0.f,0.f,0.f,0.f}};
            f32x4 accl[3] = {{0.f,0.f,0.f,0.f},{0.f,0.f,0.f,0.f},{0.f,0.f,0.f,0.f}};
#pragma unroll
            for (int kc = 0; kc < 4; ++kc) {
                f16x8 ah = pAhi[16 * wv + kc * 4 + kgrp];
                f16x8 al = pAlo[16 * wv + kc * 4 + kgrp];
#pragma unroll
                for (int g = 0; g < 3; ++g) {
                    acch[g] = __builtin_amdgcn_mfma_f32_16x16x32_f16(ah, bfh[g][kc], acch[g], 0, 0, 0);
                    accl[g] = __builtin_amdgcn_mfma_f32_16x16x32_f16(ah, bfl[g][kc], accl[g], 0, 0, 0);
                    accl[g] = __builtin_amdgcn_mfma_f32_16x16x32_f16(al, bfh[g][kc], accl[g], 0, 0, 0);
                }
            }
            // C/D: row=(lane>>4)*4+r (batch), col=lane&15 (j)
#pragma unroll
            for (int g = 0; g < 3; ++g)
#pragma unroll
                for (int r = 0; r < 4; ++r)
                    sPart[g][wv][kgrp * 4 + r][frow] = acch[g][r] + accl[g][r] * (1.0f / 2048.0f);
        }
        __syncthreads();                                   // B2: sPart visible
        // 4. fast-math gate math (sum 4 wave-partials) + publish h_{t+1} slice
        {
            float ghr = sPart[0][0][bs][j] + sPart[0][1][bs][j]
                      + sPart[0][2][bs][j] + sPart[0][3][bs][j];
            float ghz = sPart[1][0][bs][j] + sPart[1][1][bs][j]
                      + sPart[1][2][bs][j] + sPart[1][3][bs][j];
            float ghn = sPart[2][0][bs][j] + sPart[2][1][bs][j]
                      + sPart[2][2][bs][j] + sPart[2][3][bs][j];
            float gir = xsv * sWi0[j]      + mkv * sWi1[j]      + sBias[j];
            float giz = xsv * sWi0[16 + j] + mkv * sWi1[16 + j] + sBias[16 + j];
            float gin = xsv * sWi0[32 + j] + mkv * sWi1[32 + j] + sBias[32 + j];
            float rg = __fdividef(1.0f, 1.0f + __expf(-(gir + ghr)));
            float zg = __fdividef(1.0f, 1.0f + __expf(-(giz + ghz)));
            float xt = gin + rg * ghn;
            float ng = __fdividef(2.0f, 1.0f + __expf(-2.0f * xt)) - 1.0f;  // tanh(xt)
            h = (1.0f - zg) * ng + zg * h;
            f16 hi = (f16)h;
            f16 lo = (f16)((h - (float)hi) * 2048.0f);
            uint32 pk = (uint32)__builtin_bit_cast(unsigned short, hi)
                      | ((uint32)__builtin_bit_cast(unsigned short, lo) << 16);
            __hip_atomic_store(&hbufP[((size_t)((t + 1) & 1) * BN + bglob) * HN + pcol], pk,
                               __ATOMIC_RELAXED, __HIP_MEMORY_SCOPE_AGENT);
        }
        __syncthreads();   // B3: drains vmcnt(0) before s_barrier -> publishes acked at L3
        if (tid == 0)
            __hip_atomic_store(&myflags[gc], t + 1, __ATOMIC_RELAXED, __HIP_MEMORY_SCOPE_AGENT);
    }
    // 5. final FC: out[b] = sum_k h[b][k]*w_fc[k] + b_fc
    float part = h * w_fc[pcol];
#pragma unroll
    for (int o = 1; o < 16; o <<= 1) part += __shfl_xor(part, o, 64);
    if (j == 0) {
        if (gc == 0) part += b_fc[0];
        atomicAdd(&out[bglob], part);
    }
}

extern "C" void kernel_launch(void* const* d_in, const int* in_sizes, int n_in,
                              void* d_out, int out_size, void* d_ws, size_t ws_size,
                              hipStream_t stream) {
    const float* inp  = (const float*)d_in[0];
    const float* w_ih = (const float*)d_in[1];
    const float* w_hh = (const float*)d_in[2];
    const float* b_ih = (const float*)d_in[3];
    const float* b_hh = (const float*)d_in[4];
    const float* w_fc = (const float*)d_in[5];
    const float* b_fc = (const float*)d_in[6];
    float* out = (float*)d_out;
    char* ws = (char*)d_ws;
    int*    flags = (int*)ws;
    float*  scal  = (float*)(ws + OFF_SCAL);
    uint32* hbufP = (uint32*)(ws + OFF_HBUF);
    float*  xsf   = (float*)(ws + OFF_XSF);

    // zero: flags + scal + packed-h buf0 (= h_0 = 0); d_out (atomicAdd target)
    hipMemsetAsync(ws, 0, OFF_HBUF + BN * HN * 4, stream);
    hipMemsetAsync(d_out, 0, BN * sizeof(float), stream);
    k_prep<<<1, 256, 0, stream>>>(w_ih, scal);
    k_fill<<<BN, 64, 0, stream>>>(inp, scal, xsf);
    k_gru<<<GBn * GCn, 256, 0, stream>>>(inp, w_ih, w_hh, b_ih, b_hh, w_fc, b_fc,
                                         xsf, hbufP, flags, out);
}